// Round 5
// baseline (312.674 us; speedup 1.0000x reference)
//
#include <hip/hip_runtime.h>
#include <stdint.h>

// Problem constants (from reference setup_inputs)
#define M_TOK 8192
#define N_OUT 4096
#define K_IN  4096

// GEMM tiling: 256x256 tile, BK=64, double-buffered LDS (128 KiB), 8 waves 2x4
#define BM 256
#define BN 256
#define BK 64
#define NT (K_IN / BK)            // 64 K-tiles
#define BUF 32768                 // shorts per buffer (64 KiB)
#define SEC 8192                  // shorts per k-slice section (256 rows x 32)

typedef float floatx4 __attribute__((ext_vector_type(4)));
typedef float floatx16 __attribute__((ext_vector_type(16)));
typedef __bf16 bf16x8 __attribute__((ext_vector_type(8)));
typedef unsigned short ushort8_t __attribute__((ext_vector_type(8)));

#define MFMA32 __builtin_amdgcn_mfma_f32_32x32x16_bf16

// ---------- helpers ----------

__device__ __forceinline__ unsigned short f32_to_bf16_rne(float f) {
    union { float f; unsigned int u; } v; v.f = f;
    unsigned int u = v.u;
    u += 0x7FFFu + ((u >> 16) & 1u);   // round-to-nearest-even; inputs have no NaN
    return (unsigned short)(u >> 16);
}

// async global->LDS, 16 bytes per lane. LDS side is wave-uniform base + lane*16.
__device__ __forceinline__ void async_copy16(const void* g, void* l) {
    __builtin_amdgcn_global_load_lds(
        (__attribute__((address_space(1))) void*)(g),
        (__attribute__((address_space(3))) void*)(l),
        16, 0, 0);
}

// ---------- pre-pass: fp32 -> bf16 ----------

__global__ void cvt_f32_bf16_kernel(const float* __restrict__ in,
                                    unsigned short* __restrict__ out, int n8) {
    int i = blockIdx.x * 256 + threadIdx.x;
    if (i >= n8) return;
    const float4* p = (const float4*)in + (size_t)i * 2;
    float4 a = p[0];
    float4 b = p[1];
    ushort8_t o;
    o[0] = f32_to_bf16_rne(a.x); o[1] = f32_to_bf16_rne(a.y);
    o[2] = f32_to_bf16_rne(a.z); o[3] = f32_to_bf16_rne(a.w);
    o[4] = f32_to_bf16_rne(b.x); o[5] = f32_to_bf16_rne(b.y);
    o[6] = f32_to_bf16_rne(b.z); o[7] = f32_to_bf16_rne(b.w);
    *((ushort8_t*)out + i) = o;
}

// ---------- pre-pass: int32 (int8-valued) -> bf16 (exact) ----------

__global__ void cvt_i32_bf16_kernel(const int* __restrict__ in,
                                    unsigned short* __restrict__ out, int n8) {
    int i = blockIdx.x * 256 + threadIdx.x;
    if (i >= n8) return;
    const int4* p = (const int4*)in + (size_t)i * 2;
    int4 a = p[0];
    int4 b = p[1];
    ushort8_t o;
    o[0] = f32_to_bf16_rne((float)a.x); o[1] = f32_to_bf16_rne((float)a.y);
    o[2] = f32_to_bf16_rne((float)a.z); o[3] = f32_to_bf16_rne((float)a.w);
    o[4] = f32_to_bf16_rne((float)b.x); o[5] = f32_to_bf16_rne((float)b.y);
    o[6] = f32_to_bf16_rne((float)b.z); o[7] = f32_to_bf16_rne((float)b.w);
    *((ushort8_t*)out + i) = o;
}

// ---------- GEMM: C[m][n] = sum_k A[m][k]*B[n][k]; C = acc*scale[n]+bias[n] ----------
// R4's pipelined 4-phase schedule, MFMA shape switched 16x16x32 -> 32x32x16
// (m119: 2382-2495 TF vs 2176 for 16x16; half the MFMA instruction count).
// 512 threads = 8 waves (2Mx4N); per-wave output 128x64 = acc[4][2] of
// 32x32 frags. Per K-tile: 4 phases {issue next phase's 4-8 ds_read_b128 ->
// counted lgkmcnt (drains prev phase's reads only) -> 8 MFMA}. DS pipe and
// matrix pipe overlap via the one-phase-ahead register ping-pong.
//
// ds_read counts/placement, stage issues, vmcnt(4) waits and the 2
// barriers/tile are IDENTICAL to R4 (hazard matrix re-verified: every LDS
// read drains >=1 barrier before its region's overwrite issue).
//
// LDS: k-slice sections A_s0 | A_s1 | B_s0 | B_s1, 16 KiB each, PAIR-ROW
// swizzle (R3/R4-verified 0 conflicts): pair p = row>>1 (128 B) holds rows
// {2p,2p+1}; chunk (p,c): cg = c ^ (p&7). 32-row fragments read with chunk
// c(h) = (hi | (h<<1) | ((l5&1)<<2)) ^ ((l5>>1)&7) -- per-lane constant,
// same 2-lanes-per-bank-slot free pattern per 16-lane service group.
//
// 32x32x16 operand layout: A row = lane&31, k = (lane>>5)*8+j; B col =
// lane&31 (same read shape from [N][K] storage). C/D: col = lane&31,
// row = (reg&3) + 8*(reg>>2) + 4*(lane>>5)  [m74/m101].

__global__ __launch_bounds__(512, 2)
void gemm_bf16_kernel(const unsigned short* __restrict__ A,
                      const unsigned short* __restrict__ B,
                      const float* __restrict__ scales,
                      const float* __restrict__ bias,
                      float* __restrict__ C) {
    __shared__ __align__(16) unsigned short lds[2 * BUF];   // 128 KiB

    const int tid = threadIdx.x;

    // T1: bijective XCD swizzle (nwg = 512, divisible by 8), bn-fastest.
    const int nwg = (M_TOK / BM) * (N_OUT / BN);   // 32*16 = 512
    const int cpx = nwg / 8;                        // 64
    const int wg  = (blockIdx.x % 8) * cpx + blockIdx.x / 8;
    const int bn  = wg & 15;                        // N_OUT/BN = 16
    const int bm  = wg >> 4;                        // 0..31

    const int lane = tid & 63;
    const int wave = tid >> 6;          // 0..7
    const int wm   = wave >> 2;         // 0..1 -> rows wm*128
    const int wn   = wave & 3;          // 0..3 -> cols wn*64

    // ---- staging addressing (loop-invariant; R3-verified) ----
    const int t8 = tid >> 3;                        // 0..63
    const int cg = (tid & 7) ^ (t8 & 7);            // unswizzled chunk in pair
    const int grow0 = 2 * t8 + (cg >> 2);           // row within 128-row issue
    const int gcol0 = (cg & 3) * 8;                 // shorts within k-slice
    const unsigned short* aP = A + (size_t)(bm * BM + grow0) * K_IN + gcol0;
    const unsigned short* bP = B + (size_t)(bn * BN + grow0) * K_IN + gcol0;

    auto stA = [&](int tt, int s) {
        unsigned short* d = &lds[(tt & 1) * BUF + s * SEC + tid * 8];
        const unsigned short* g = aP + tt * BK + s * 32;
        async_copy16(g, d);
        async_copy16(g + (size_t)128 * K_IN, d + 4096);
    };
    auto stB = [&](int tt, int s) {
        unsigned short* d = &lds[(tt & 1) * BUF + 2 * SEC + s * SEC + tid * 8];
        const unsigned short* g = bP + tt * BK + s * 32;
        async_copy16(g, d);
        async_copy16(g + (size_t)128 * K_IN, d + 4096);
    };

    // ---- fragment read addressing (loop-invariant) ----
    const int l5 = lane & 31;
    const int hi = lane >> 5;                       // 0..1
    const int p7 = (l5 >> 1) & 7;
    const int c0 = (hi | ((l5 & 1) << 2)) ^ p7;     // chunk for h=0; h=1 is c0^2
    const int aR = (wm * 64 + (l5 >> 1)) * 64;              // within A_s section
    const int bR = 2 * SEC + (wn * 32 + (l5 >> 1)) * 64;    // B_s0 base in buffer

    // af[m2*2+h], bf[n*2+h]
    floatx16 acc[4][2] = {};
    bf16x8 afA[4], afB[4], bfA[4], bfB[4];

    // read A half (section s, m-half mh) into dst[4]
#define RD_A(dst, base, s, mh)                                                   \
    dst[0] = *(const bf16x8*)((base) + (s) * SEC + aR + (2*(mh)  ) * 1024 + c0 * 8);      \
    dst[1] = *(const bf16x8*)((base) + (s) * SEC + aR + (2*(mh)  ) * 1024 + (c0^2) * 8);  \
    dst[2] = *(const bf16x8*)((base) + (s) * SEC + aR + (2*(mh)+1) * 1024 + c0 * 8);      \
    dst[3] = *(const bf16x8*)((base) + (s) * SEC + aR + (2*(mh)+1) * 1024 + (c0^2) * 8);
    // read B (section s) into dst[4]
#define RD_B(dst, base, s)                                                       \
    dst[0] = *(const bf16x8*)((base) + (s) * SEC + bR + c0 * 8);                 \
    dst[1] = *(const bf16x8*)((base) + (s) * SEC + bR + (c0^2) * 8);             \
    dst[2] = *(const bf16x8*)((base) + (s) * SEC + bR + 1024 + c0 * 8);          \
    dst[3] = *(const bf16x8*)((base) + (s) * SEC + bR + 1024 + (c0^2) * 8);
    // 8 MFMA: acc[2*mh+m2][n] += af[m2*2+h] * bf[n*2+h]
#define MM(mh, af, bf)                                                           \
    acc[2*(mh)  ][0] = MFMA32(af[0], bf[0], acc[2*(mh)  ][0], 0, 0, 0);          \
    acc[2*(mh)  ][1] = MFMA32(af[0], bf[2], acc[2*(mh)  ][1], 0, 0, 0);          \
    acc[2*(mh)+1][0] = MFMA32(af[2], bf[0], acc[2*(mh)+1][0], 0, 0, 0);          \
    acc[2*(mh)+1][1] = MFMA32(af[2], bf[2], acc[2*(mh)+1][1], 0, 0, 0);          \
    acc[2*(mh)  ][0] = MFMA32(af[1], bf[1], acc[2*(mh)  ][0], 0, 0, 0);          \
    acc[2*(mh)  ][1] = MFMA32(af[1], bf[3], acc[2*(mh)  ][1], 0, 0, 0);          \
    acc[2*(mh)+1][0] = MFMA32(af[3], bf[1], acc[2*(mh)+1][0], 0, 0, 0);          \
    acc[2*(mh)+1][1] = MFMA32(af[3], bf[3], acc[2*(mh)+1][1], 0, 0, 0);

    // ---- prologue: stage tile 0, drain k0, read P1(0)'s fragments ----
    stA(0, 0); stB(0, 0); stA(0, 1); stB(0, 1);
    asm volatile("s_waitcnt vmcnt(4)" ::: "memory");   // k0(0) landed
    __builtin_amdgcn_s_barrier();
    asm volatile("" ::: "memory");
    RD_A(afA, lds, 0, 0);
    RD_B(bfA, lds, 0);

#pragma unroll 1
    for (int t = 0; t < NT; ++t) {
        const unsigned short* Lb  = lds + (t & 1) * BUF;
        const unsigned short* Lb2 = lds + ((t + 1) & 1) * BUF;
        const bool pf = (t + 1 < NT);

        // ---- P1: MFMA(afA,bfA)->acc[0,1] | read A(s0,mh1)->afB | stage A0' ----
        if (pf) stA(t + 1, 0);
        RD_A(afB, Lb, 0, 1);
        asm volatile("s_waitcnt lgkmcnt(4)" ::: "memory");
        __builtin_amdgcn_sched_barrier(0);
        __builtin_amdgcn_s_setprio(1);
        MM(0, afA, bfA);
        __builtin_amdgcn_s_setprio(0);

        // ---- P2: stage B0' | vmcnt+barrier | read A(s1,mh0)->afA, B(s1)->bfB |
        //          MFMA(afB,bfA)->acc[2,3] ----
        if (pf) stB(t + 1, 0);
        if (pf) asm volatile("s_waitcnt vmcnt(4)" ::: "memory");
        else    asm volatile("s_waitcnt vmcnt(0)" ::: "memory");
        __builtin_amdgcn_s_barrier();
        asm volatile("" ::: "memory");
        RD_A(afA, Lb, 1, 0);
        RD_B(bfB, Lb, 1);
        asm volatile("s_waitcnt lgkmcnt(8)" ::: "memory");
        __builtin_amdgcn_sched_barrier(0);
        __builtin_amdgcn_s_setprio(1);
        MM(1, afB, bfA);
        __builtin_amdgcn_s_setprio(0);

        // ---- P3: MFMA(afA,bfB)->acc[0,1] | read A(s1,mh1)->afB | stage A1' ----
        if (pf) stA(t + 1, 1);
        RD_A(afB, Lb, 1, 1);
        asm volatile("s_waitcnt lgkmcnt(4)" ::: "memory");
        __builtin_amdgcn_sched_barrier(0);
        __builtin_amdgcn_s_setprio(1);
        MM(0, afA, bfB);
        __builtin_amdgcn_s_setprio(0);

        // ---- P4: stage B1' | vmcnt+barrier | read next A(s0,mh0)->afA, B(s0)->bfA |
        //          MFMA(afB,bfB)->acc[2,3] ----
        if (pf) {
            stB(t + 1, 1);
            asm volatile("s_waitcnt vmcnt(4)" ::: "memory");  // k0(t+1) landed
            __builtin_amdgcn_s_barrier();
            asm volatile("" ::: "memory");
            RD_A(afA, Lb2, 0, 0);
            RD_B(bfA, Lb2, 0);
            asm volatile("s_waitcnt lgkmcnt(8)" ::: "memory");
        } else {
            asm volatile("s_waitcnt lgkmcnt(0)" ::: "memory");
        }
        __builtin_amdgcn_sched_barrier(0);
        __builtin_amdgcn_s_setprio(1);
        MM(1, afB, bfB);
        __builtin_amdgcn_s_setprio(0);
    }

    // ---- epilogue: 32x32 C/D layout col = lane&31, row = (reg&3)+8*(reg>>2)+4*hi ----
    const int row0 = bm * BM + wm * 128 + 4 * hi;
    const int col0 = bn * BN + wn * 64 + l5;
#pragma unroll
    for (int nf = 0; nf < 2; ++nf) {
        const int n  = col0 + nf * 32;
        const float sc = scales[n];
        const float bi = bias[n];
#pragma unroll
        for (int mf = 0; mf < 4; ++mf) {
            const int mbase = row0 + mf * 32;
#pragma unroll
            for (int reg = 0; reg < 16; ++reg) {
                const int m = mbase + (reg & 3) + 8 * (reg >> 2);
                C[(size_t)m * N_OUT + n] = acc[mf][nf][reg] * sc + bi;
            }
        }
    }
}

// ---------- launch ----------

extern "C" void kernel_launch(void* const* d_in, const int* in_sizes, int n_in,
                              void* d_out, int out_size, void* d_ws, size_t ws_size,
                              hipStream_t stream) {
    const float* x      = (const float*)d_in[0];
    const int*   wq     = (const int*)d_in[1];
    const float* scales = (const float*)d_in[2];
    const float* bias   = (const float*)d_in[3];
    float*       out    = (float*)d_out;

    unsigned short* xb = (unsigned short*)d_ws;                       // 64 MiB
    unsigned short* wb = xb + (size_t)M_TOK * K_IN;                   // 32 MiB
    // ws needed: (8192*4096 + 4096*4096) * 2 = 96 MiB

    const int nx8 = (M_TOK * K_IN) / 8;   // 4194304
    const int nw8 = (N_OUT * K_IN) / 8;   // 2097152
    cvt_f32_bf16_kernel<<<nx8 / 256, 256, 0, stream>>>(x, xb, nx8);
    cvt_i32_bf16_kernel<<<nw8 / 256, 256, 0, stream>>>(wq, wb, nw8);

    const int grid = (M_TOK / BM) * (N_OUT / BN);   // 32 * 16 = 512
    gemm_bf16_kernel<<<grid, 512, 0, stream>>>(xb, wb, scales, bias, out);
}

// Round 6
// 286.904 us; speedup vs baseline: 1.0898x; 1.0898x over previous
//
#include <hip/hip_runtime.h>
#include <stdint.h>

// Problem constants (from reference setup_inputs)
#define M_TOK 8192
#define N_OUT 4096
#define K_IN  4096

// GEMM tiling: 256x256 tile, BK=64, double-buffered LDS (128 KiB), 8 waves 2x4
#define BM 256
#define BN 256
#define BK 64
#define NT (K_IN / BK)            // 64 K-tiles
#define BUF 32768                 // shorts per buffer (64 KiB)
#define SEC 8192                  // shorts per k-slice section (256 rows x 32)

typedef float floatx4 __attribute__((ext_vector_type(4)));
typedef __bf16 bf16x8 __attribute__((ext_vector_type(8)));
typedef unsigned short ushort8_t __attribute__((ext_vector_type(8)));

#define MFMA16 __builtin_amdgcn_mfma_f32_16x16x32_bf16

// ---------- helpers ----------

__device__ __forceinline__ unsigned short f32_to_bf16_rne(float f) {
    union { float f; unsigned int u; } v; v.f = f;
    unsigned int u = v.u;
    u += 0x7FFFu + ((u >> 16) & 1u);   // round-to-nearest-even; inputs have no NaN
    return (unsigned short)(u >> 16);
}

// async global->LDS, 16 bytes per lane. LDS side is wave-uniform base + lane*16.
__device__ __forceinline__ void async_copy16(const void* g, void* l) {
    __builtin_amdgcn_global_load_lds(
        (__attribute__((address_space(1))) void*)(g),
        (__attribute__((address_space(3))) void*)(l),
        16, 0, 0);
}

// ---------- pre-pass: fp32 -> bf16 ----------

__global__ void cvt_f32_bf16_kernel(const float* __restrict__ in,
                                    unsigned short* __restrict__ out, int n8) {
    int i = blockIdx.x * 256 + threadIdx.x;
    if (i >= n8) return;
    const float4* p = (const float4*)in + (size_t)i * 2;
    float4 a = p[0];
    float4 b = p[1];
    ushort8_t o;
    o[0] = f32_to_bf16_rne(a.x); o[1] = f32_to_bf16_rne(a.y);
    o[2] = f32_to_bf16_rne(a.z); o[3] = f32_to_bf16_rne(a.w);
    o[4] = f32_to_bf16_rne(b.x); o[5] = f32_to_bf16_rne(b.y);
    o[6] = f32_to_bf16_rne(b.z); o[7] = f32_to_bf16_rne(b.w);
    *((ushort8_t*)out + i) = o;
}

// ---------- pre-pass: int32 (int8-valued) -> bf16 (exact) ----------

__global__ void cvt_i32_bf16_kernel(const int* __restrict__ in,
                                    unsigned short* __restrict__ out, int n8) {
    int i = blockIdx.x * 256 + threadIdx.x;
    if (i >= n8) return;
    const int4* p = (const int4*)in + (size_t)i * 2;
    int4 a = p[0];
    int4 b = p[1];
    ushort8_t o;
    o[0] = f32_to_bf16_rne((float)a.x); o[1] = f32_to_bf16_rne((float)a.y);
    o[2] = f32_to_bf16_rne((float)a.z); o[3] = f32_to_bf16_rne((float)a.w);
    o[4] = f32_to_bf16_rne((float)b.x); o[5] = f32_to_bf16_rne((float)b.y);
    o[6] = f32_to_bf16_rne((float)b.z); o[7] = f32_to_bf16_rne((float)b.w);
    *((ushort8_t*)out + i) = o;
}

// ---------- GEMM: C[m][n] = sum_k A[m][k]*B[n][k]; C = acc*scale[n]+bias[n] ----------
// R4's register-pipelined 4-phase loop (16x16x32 MFMA, proven 0-conflict
// pair-row swizzle) with SINGLE-SYNC TILES: all 8 stage loads for tile t+1
// are issued in P1/P2, so one {lgkmcnt(0) + vmcnt(0) + s_barrier} at the tile
// boundary replaces R4's two barrier-sets. Both drains are cheap: the vmcnt
// targets loads issued >=2 phases (~2300 cyc) earlier; the lgkmcnt targets
// 4 ds_reads issued 1 phase earlier.
//
// lgkm ledger (DS in-order per wave): P1 wait lgkmcnt(4) [drains prev P4's 8],
// P2 lgkmcnt(8) [drains P1's 4], P3 lgkmcnt(4) [drains P2's 8], boundary
// lgkmcnt(0) [drains P3's 4]. MFMA4 runs with next tile's 8 reads in flight
// (disjoint registers).
//
// Hazards: (a) stage(t+1)->buf^1 vs t-1's buf^1 reads: those were lgkm-drained
// before the t-1 boundary barrier, stage issues come after it. (b) t's buf
// reads vs stage(t+2)->buf at t+1's P1: all buf reads lgkm-drained (P3's via
// the boundary lgkmcnt(0)) before t's boundary barrier. (c) staged-data
// visibility: every wave executes vmcnt(0) then barrier before any wave reads
// tile t+1.
//
// LDS: k-slice sections A_s0 | A_s1 | B_s0 | B_s1, 16 KiB each, PAIR-ROW
// swizzle (R3/R4-verified 0 conflicts): pair p = row>>1 (128 B) holds rows
// {2p,2p+1}; chunk (p,c): cg = c ^ (p&7); inverse on the per-lane GLOBAL
// source, linear LDS dest. Each ds_read_b128 covers one contiguous 1024 B
// window exactly once (the property R5's 32x32 reads lacked -> 2.5e7
// conflicts; do not regress this).

__global__ __launch_bounds__(512, 2)
void gemm_bf16_kernel(const unsigned short* __restrict__ A,
                      const unsigned short* __restrict__ B,
                      const float* __restrict__ scales,
                      const float* __restrict__ bias,
                      float* __restrict__ C) {
    __shared__ __align__(16) unsigned short lds[2 * BUF];   // 128 KiB

    const int tid = threadIdx.x;

    // T1: bijective XCD swizzle (nwg = 512, divisible by 8), bn-fastest.
    const int nwg = (M_TOK / BM) * (N_OUT / BN);   // 32*16 = 512
    const int cpx = nwg / 8;                        // 64
    const int wg  = (blockIdx.x % 8) * cpx + blockIdx.x / 8;
    const int bn  = wg & 15;                        // N_OUT/BN = 16
    const int bm  = wg >> 4;                        // 0..31

    const int lane = tid & 63;
    const int wave = tid >> 6;          // 0..7
    const int wm   = wave >> 2;         // 0..1 -> rows wm*128
    const int wn   = wave & 3;          // 0..3 -> cols wn*64

    // ---- staging addressing (loop-invariant; R3-verified) ----
    const int t8 = tid >> 3;                        // 0..63
    const int cg = (tid & 7) ^ (t8 & 7);            // unswizzled chunk in pair
    const int grow0 = 2 * t8 + (cg >> 2);           // row within 128-row issue
    const int gcol0 = (cg & 3) * 8;                 // shorts within k-slice
    const unsigned short* aP = A + (size_t)(bm * BM + grow0) * K_IN + gcol0;
    const unsigned short* bP = B + (size_t)(bn * BN + grow0) * K_IN + gcol0;

    auto stA = [&](int tt, int s) {
        unsigned short* d = &lds[(tt & 1) * BUF + s * SEC + tid * 8];
        const unsigned short* g = aP + tt * BK + s * 32;
        async_copy16(g, d);
        async_copy16(g + (size_t)128 * K_IN, d + 4096);
    };
    auto stB = [&](int tt, int s) {
        unsigned short* d = &lds[(tt & 1) * BUF + 2 * SEC + s * SEC + tid * 8];
        const unsigned short* g = bP + tt * BK + s * 32;
        async_copy16(g, d);
        async_copy16(g + (size_t)128 * K_IN, d + 4096);
    };

    // ---- fragment read addressing (loop-invariant) ----
    // Frag row R: pair p = R>>1, c = ((R&1)*4 + q) ^ ((R>>1)&7).
    const int r16 = lane & 15;
    const int q   = lane >> 4;                      // 0..3
    const int cr  = (((r16 & 1) << 2) + q) ^ ((r16 >> 1) & 7);
    const int aOff = (wm * 64 + (r16 >> 1)) * 64 + cr * 8;
    const int bOff = 2 * SEC + (wn * 32 + (r16 >> 1)) * 64 + cr * 8;

    floatx4 acc[8][4] = {};
    bf16x8 afA[4], afB[4], bfA[4], bfB[4];

    // ---- prologue: stage tile 0, drain, read P1(0)'s fragments ----
    stA(0, 0); stA(0, 1); stB(0, 0); stB(0, 1);
    asm volatile("s_waitcnt vmcnt(0)" ::: "memory");
    __builtin_amdgcn_s_barrier();
    asm volatile("" ::: "memory");
    {
        const unsigned short* ar = lds + aOff;
        const unsigned short* br = lds + bOff;
#pragma unroll
        for (int i = 0; i < 4; ++i) afA[i] = *(const bf16x8*)(ar + i * 512);
#pragma unroll
        for (int j = 0; j < 4; ++j) bfA[j] = *(const bf16x8*)(br + j * 512);
    }

#pragma unroll 1
    for (int t = 0; t < NT; ++t) {
        const unsigned short* ar  = lds + (t & 1) * BUF + aOff;
        const unsigned short* br  = lds + (t & 1) * BUF + bOff;
        const unsigned short* ar2 = lds + ((t + 1) & 1) * BUF + aOff;
        const unsigned short* br2 = lds + ((t + 1) & 1) * BUF + bOff;
        const bool pf = (t + 1 < NT);

        // ---- P1: stage A(t+1) both slices | read A47s0->afB |
        //          MFMA(afA,bfA)->acc[0..3] ----
        if (pf) { stA(t + 1, 0); stA(t + 1, 1); }
#pragma unroll
        for (int i = 0; i < 4; ++i) afB[i] = *(const bf16x8*)(ar + (4 + i) * 512);
        asm volatile("s_waitcnt lgkmcnt(4)" ::: "memory");
        __builtin_amdgcn_sched_barrier(0);
        __builtin_amdgcn_s_setprio(1);
#pragma unroll
        for (int i = 0; i < 4; ++i)
#pragma unroll
            for (int j = 0; j < 4; ++j)
                acc[i][j] = MFMA16(afA[i], bfA[j], acc[i][j], 0, 0, 0);
        __builtin_amdgcn_s_setprio(0);

        // ---- P2: stage B(t+1) both slices | read A03s1->afA, Bs1->bfB |
        //          MFMA(afB,bfA)->acc[4..7] ----
        if (pf) { stB(t + 1, 0); stB(t + 1, 1); }
#pragma unroll
        for (int i = 0; i < 4; ++i) afA[i] = *(const bf16x8*)(ar + SEC + i * 512);
#pragma unroll
        for (int j = 0; j < 4; ++j) bfB[j] = *(const bf16x8*)(br + SEC + j * 512);
        asm volatile("s_waitcnt lgkmcnt(8)" ::: "memory");
        __builtin_amdgcn_sched_barrier(0);
        __builtin_amdgcn_s_setprio(1);
#pragma unroll
        for (int i = 0; i < 4; ++i)
#pragma unroll
            for (int j = 0; j < 4; ++j)
                acc[4 + i][j] = MFMA16(afB[i], bfA[j], acc[4 + i][j], 0, 0, 0);
        __builtin_amdgcn_s_setprio(0);

        // ---- P3: read A47s1->afB | MFMA(afA,bfB)->acc[0..3] ----
#pragma unroll
        for (int i = 0; i < 4; ++i) afB[i] = *(const bf16x8*)(ar + SEC + (4 + i) * 512);
        asm volatile("s_waitcnt lgkmcnt(4)" ::: "memory");
        __builtin_amdgcn_sched_barrier(0);
        __builtin_amdgcn_s_setprio(1);
#pragma unroll
        for (int i = 0; i < 4; ++i)
#pragma unroll
            for (int j = 0; j < 4; ++j)
                acc[i][j] = MFMA16(afA[i], bfB[j], acc[i][j], 0, 0, 0);
        __builtin_amdgcn_s_setprio(0);

        // ---- P4: single tile-boundary sync, then read next tile's s0 frags |
        //          MFMA(afB,bfB)->acc[4..7] (runs with 8 reads in flight) ----
        asm volatile("s_waitcnt vmcnt(0) lgkmcnt(0)" ::: "memory");
        __builtin_amdgcn_s_barrier();
        asm volatile("" ::: "memory");
        if (pf) {
#pragma unroll
            for (int i = 0; i < 4; ++i) afA[i] = *(const bf16x8*)(ar2 + i * 512);
#pragma unroll
            for (int j = 0; j < 4; ++j) bfA[j] = *(const bf16x8*)(br2 + j * 512);
        }
        __builtin_amdgcn_sched_barrier(0);
        __builtin_amdgcn_s_setprio(1);
#pragma unroll
        for (int i = 0; i < 4; ++i)
#pragma unroll
            for (int j = 0; j < 4; ++j)
                acc[4 + i][j] = MFMA16(afB[i], bfB[j], acc[4 + i][j], 0, 0, 0);
        __builtin_amdgcn_s_setprio(0);
    }

    // ---- epilogue: C/D layout col = lane&15, row = (lane>>4)*4 + reg ----
    const int row0 = bm * BM + wm * 128 + q * 4;
    const int col0 = bn * BN + wn * 64 + r16;
#pragma unroll
    for (int fc = 0; fc < 4; ++fc) {
        const int n  = col0 + fc * 16;
        const float sc = scales[n];
        const float bi = bias[n];
#pragma unroll
        for (int fr = 0; fr < 8; ++fr) {
            const int m = row0 + fr * 16;
#pragma unroll
            for (int r = 0; r < 4; ++r)
                C[(size_t)(m + r) * N_OUT + n] = acc[fr][fc][r] * sc + bi;
        }
    }
}

// ---------- launch ----------

extern "C" void kernel_launch(void* const* d_in, const int* in_sizes, int n_in,
                              void* d_out, int out_size, void* d_ws, size_t ws_size,
                              hipStream_t stream) {
    const float* x      = (const float*)d_in[0];
    const int*   wq     = (const int*)d_in[1];
    const float* scales = (const float*)d_in[2];
    const float* bias   = (const float*)d_in[3];
    float*       out    = (float*)d_out;

    unsigned short* xb = (unsigned short*)d_ws;                       // 64 MiB
    unsigned short* wb = xb + (size_t)M_TOK * K_IN;                   // 32 MiB
    // ws needed: (8192*4096 + 4096*4096) * 2 = 96 MiB

    const int nx8 = (M_TOK * K_IN) / 8;   // 4194304
    const int nw8 = (N_OUT * K_IN) / 8;   // 2097152
    cvt_f32_bf16_kernel<<<nx8 / 256, 256, 0, stream>>>(x, xb, nx8);
    cvt_i32_bf16_kernel<<<nw8 / 256, 256, 0, stream>>>(wq, wb, nw8);

    const int grid = (M_TOK / BM) * (N_OUT / BN);   // 32 * 16 = 512
    gemm_bf16_kernel<<<grid, 512, 0, stream>>>(xb, wb, scales, bias, out);
}